// Round 10
// baseline (432.267 us; speedup 1.0000x reference)
//
#include <hip/hip_runtime.h>
#include <math.h>

// ALL floating-point in this file must be strict IEEE f32, no FMA contraction.
// hipcc default is -ffp-contract=fast-honor-pragmas; this pragma (file scope +
// repeated at block scope) keeps every mul/add emitted here contract-free.
// Do NOT use __fadd_rn/__fmul_rn wrappers: their inline bodies live in HIP
// headers outside this pragma's lexical scope and pick up contract flags.
#pragma clang fp contract(off)

// Exact f32 of the reference's (dr + pad) scalars:
//   pad = 2, diag offset = np.round(sin(pi/4), 5) = 0.70711 (f64); f64 sum
//   (dr+pad) cast once to f32.
#define OFF_A ((float)(2.0 - 0.70711))   // 1.29289 -> f32
#define OFF_B ((float)(2.0 + 0.70711))   // 2.70711 -> f32

static __device__ __forceinline__ float cvt_u8(float v) {
#pragma clang fp contract(off)
    // clip(floor(x*255), 0, 255) — strict f32 (mul feeds floorf; not fusable)
    float m = v * 255.0f;
    return fminf(fmaxf(floorf(m), 0.0f), 255.0f);
}

// Reference bilinear, STRICT f32, Python op order, zero fusion:
//   ((1-fr)*(1-fc))*v00 + ((1-fr)*fc)*v01 + (fr*(1-fc))*v10 + (fr*fc)*v11
// left-associated adds; (val - c) >= 0 strict.
static __device__ __forceinline__ int bilin_ge(float fr, float fc,
                                               float v00, float v01,
                                               float v10, float v11,
                                               float c) {
#pragma clang fp contract(off)
    float omr = 1.0f - fr;
    float omc = 1.0f - fc;
    float w00 = omr * omc;
    float w01 = omr * fc;
    float w10 = fr * omc;
    float w11 = fr * fc;
    float t0 = w00 * v00;
    float t1 = w01 * v01;
    float t2 = w10 * v10;
    float t3 = w11 * v11;
    float s1 = t0 + t1;
    float s2 = s1 + t2;
    float val = s2 + t3;
    float d = val - c;
    return d >= 0.0f;
}

__global__ __launch_bounds__(256)
void lbp_uniform_kernel(const float* __restrict__ x, float* __restrict__ out, int total) {
#pragma clang fp contract(off)
    const int Wd = 1024, Hd = 1024;
    int idx = blockIdx.x * 256 + threadIdx.x;
    if (idx >= total) return;

    int col  = idx & (Wd - 1);
    int row  = (idx >> 10) & (Hd - 1);
    const float* img = x + ((size_t)(idx >> 20) << 20);  // channel base (H*W = 2^20)

    const float* rc = img + (size_t)row * Wd;
    const float* rm = rc - Wd;
    const float* rp = rc + Wd;
    bool rmv = (row > 0), rpv = (row < Hd - 1);
    bool cmv = (col > 0), cpv = (col < Wd - 1);
    int cm = col - 1, cp = col + 1;

    // 3x3 neighborhood as uint8-valued floats; zero padding outside.
    float vC  = cvt_u8(rc[col]);
    float vE  = cpv ? cvt_u8(rc[cp]) : 0.0f;
    float vW_ = cmv ? cvt_u8(rc[cm]) : 0.0f;
    float vN  = rmv ? cvt_u8(rm[col]) : 0.0f;
    float vS  = rpv ? cvt_u8(rp[col]) : 0.0f;
    float vNE = (rmv && cpv) ? cvt_u8(rm[cp]) : 0.0f;
    float vNW = (rmv && cmv) ? cvt_u8(rm[cm]) : 0.0f;
    float vSE = (rpv && cpv) ? cvt_u8(rp[cp]) : 0.0f;
    float vSW = (rpv && cmv) ? cvt_u8(rp[cm]) : 0.0f;

    // fr/fc strict f32, exactly as the ref: r = f32(row) + f32(off);
    // fr = r - floor(r) (exact by Sterbenz). Row-magnitude-dependent.
    float rowf = (float)row, colf = (float)col;
    float rA = rowf + OFF_A; float frA = rA - floorf(rA);
    float rB = rowf + OFF_B; float frB = rB - floorf(rB);
    float cA = colf + OFF_A; float fcA = cA - floorf(cA);
    float cB = colf + OFF_B; float fcB = cB - floorf(cB);

    // Sample k -> (dr,dc): 0:(0,+1) 1:(-.7,+.7) 2:(-1,0) 3:(-.7,-.7)
    //                      4:(0,-1) 5:(+.7,-.7) 6:(+1,0) 7:(+.7,+.7)
    // Axis samples: fr=fc=0 -> exact pixel compare (order-independent).
    // Diagonal bilinear corners (v00,v01 / v10,v11):
    //  k1: N, NE / C, E   (fr=frA, fc=fcB)
    //  k3: NW, N / W, C   (fr=frA, fc=fcA)
    //  k5: W, C / SW, S   (fr=frB, fc=fcA)
    //  k7: C, E / S, SE   (fr=frB, fc=fcB)
    int b0 = (vE  >= vC);
    int b1 = bilin_ge(frA, fcB, vN,  vNE, vC,  vE,  vC);
    int b2 = (vN  >= vC);
    int b3 = bilin_ge(frA, fcA, vNW, vN,  vW_, vC,  vC);
    int b4 = (vW_ >= vC);
    int b5 = bilin_ge(frB, fcA, vW_, vC,  vSW, vS,  vC);
    int b6 = (vS  >= vC);
    int b7 = bilin_ge(frB, fcB, vC,  vE,  vS,  vSE, vC);

    int ones    = b0 + b1 + b2 + b3 + b4 + b5 + b6 + b7;
    int changes = (b0 ^ b1) + (b1 ^ b2) + (b2 ^ b3) + (b3 ^ b4)
                + (b4 ^ b5) + (b5 ^ b6) + (b6 ^ b7) + (b7 ^ b0);
    int lbp = (changes <= 2) ? ones : 9;

    // Correctly-rounded k/255 (compile-time folded; no double-rounding hazard
    // for k/255 — repeating-bit tails are never near-halfway at f32 cut).
    const float lut[10] = {
        (float)(0.0 / 255.0), (float)(1.0 / 255.0), (float)(2.0 / 255.0),
        (float)(3.0 / 255.0), (float)(4.0 / 255.0), (float)(5.0 / 255.0),
        (float)(6.0 / 255.0), (float)(7.0 / 255.0), (float)(8.0 / 255.0),
        (float)(9.0 / 255.0)
    };
    out[idx] = lut[lbp];
}

extern "C" void kernel_launch(void* const* d_in, const int* in_sizes, int n_in,
                              void* d_out, int out_size, void* d_ws, size_t ws_size,
                              hipStream_t stream) {
    const float* x = (const float*)d_in[0];
    float* out = (float*)d_out;
    int total = out_size;  // 32*1024*1024
    int blocks = (total + 255) / 256;
    lbp_uniform_kernel<<<blocks, 256, 0, stream>>>(x, out, total);
}

// Round 11
// 262.485 us; speedup vs baseline: 1.6468x; 1.6468x over previous
//
#include <hip/hip_runtime.h>
#include <math.h>

// ALL floating-point here must be strict IEEE f32, no FMA contraction.
// (Round-10 lesson: __fadd_rn/__fmul_rn header wrappers pick up contract
// flags from the header's pragma context — use plain ops in THIS file only.)
#pragma clang fp contract(off)

// Exact f32 of the reference's (dr + pad): pad=2, off=np.round(sin(pi/4),5)
#define OFF_A ((float)(2.0 - 0.70711))   // 1.29289 -> f32
#define OFF_B ((float)(2.0 + 0.70711))   // 2.70711 -> f32

static __device__ __forceinline__ float cvt_u8(float v) {
#pragma clang fp contract(off)
    // Reference: clip(floor(x*255), 0, 255). Input is jax.random.uniform
    // [0,1): x*255 in [0, 254.99998] -> floor in [0,254]; clamps are no-ops
    // and elided. Strict f32 mul (feeds floorf; not fusable anyway).
    return floorf(v * 255.0f);
}

// Reference bilinear, STRICT f32, token-identical op sequence to the
// round-10 passing kernel: w=omr*omc etc (omr/omc hoisted, same values),
// t=w*v, left-associated adds, (val-c)>=0. Zero fusion.
static __device__ __forceinline__ int bilin_ge(float fr, float fc,
                                               float omr, float omc,
                                               float v00, float v01,
                                               float v10, float v11,
                                               float c) {
#pragma clang fp contract(off)
    float w00 = omr * omc;
    float w01 = omr * fc;
    float w10 = fr * omc;
    float w11 = fr * fc;
    float t0 = w00 * v00;
    float t1 = w01 * v01;
    float t2 = w10 * v10;
    float t3 = w11 * v11;
    float s1 = t0 + t1;
    float s2 = s1 + t2;
    float val = s2 + t3;
    float d = val - c;
    return d >= 0.0f;
}

__global__ __launch_bounds__(256)
void lbp_uniform_kernel4(const float* __restrict__ x, float* __restrict__ out,
                         int nquads) {
#pragma clang fp contract(off)
    int q = blockIdx.x * 256 + threadIdx.x;   // one thread = 4 pixels in a row
    if (q >= nquads) return;

    int col0 = (q & 255) << 2;                 // 256 quads per 1024-wide row
    int row  = (q >> 8) & 1023;
    const float* img = x + ((size_t)(q >> 18) << 20);  // channel base (2^18 quads/ch)

    const float* rc = img + ((size_t)row << 10);
    bool rmv = (row > 0), rpv = (row < 1023);
    const float* rm = rmv ? rc - 1024 : rc;    // clamped: loads stay in-bounds
    const float* rp = rpv ? rc + 1024 : rc;

    bool lv = (col0 > 0);                      // left neighbor col0-1 exists
    bool rv = (col0 < 1020);                   // right neighbor col0+4 exists
    int cl = lv ? col0 - 1 : col0;             // clamped addresses
    int cr = rv ? col0 + 4 : col0 + 3;

    // 6 raw values per row: [L][x][y][z][w][R]
    float4 m4 = *reinterpret_cast<const float4*>(rm + col0);
    float4 c4 = *reinterpret_cast<const float4*>(rc + col0);
    float4 p4 = *reinterpret_cast<const float4*>(rp + col0);
    float mL = rm[cl], mR = rm[cr];
    float cL = rc[cl], cR = rc[cr];
    float pL = rp[cl], pR = rp[cr];

    // Convert once per loaded value; zero outside the image.
    float T[6], M[6], B[6];
    T[0] = (rmv && lv) ? cvt_u8(mL)   : 0.0f;
    T[1] = rmv         ? cvt_u8(m4.x) : 0.0f;
    T[2] = rmv         ? cvt_u8(m4.y) : 0.0f;
    T[3] = rmv         ? cvt_u8(m4.z) : 0.0f;
    T[4] = rmv         ? cvt_u8(m4.w) : 0.0f;
    T[5] = (rmv && rv) ? cvt_u8(mR)   : 0.0f;
    M[0] = lv ? cvt_u8(cL) : 0.0f;
    M[1] = cvt_u8(c4.x);
    M[2] = cvt_u8(c4.y);
    M[3] = cvt_u8(c4.z);
    M[4] = cvt_u8(c4.w);
    M[5] = rv ? cvt_u8(cR) : 0.0f;
    B[0] = (rpv && lv) ? cvt_u8(pL)   : 0.0f;
    B[1] = rpv         ? cvt_u8(p4.x) : 0.0f;
    B[2] = rpv         ? cvt_u8(p4.y) : 0.0f;
    B[3] = rpv         ? cvt_u8(p4.z) : 0.0f;
    B[4] = rpv         ? cvt_u8(p4.w) : 0.0f;
    B[5] = (rpv && rv) ? cvt_u8(pR)   : 0.0f;

    // Row-fractional parts: shared by the 4 pixels (same row).
    // fr = r - floor(r) with r = f32(row) + f32(off); exact per reference.
    float rowf = (float)row;
    float rA = rowf + OFF_A; float frA = rA - floorf(rA);
    float rB = rowf + OFF_B; float frB = rB - floorf(rB);
    float omrA = 1.0f - frA;
    float omrB = 1.0f - frB;

    // k -> (dr,dc): 0:(0,+1) 1:(-.7,+.7) 2:(-1,0) 3:(-.7,-.7)
    //               4:(0,-1) 5:(+.7,-.7) 6:(+1,0) 7:(+.7,+.7)
    // Diagonal corners (v00,v01 / v10,v11):
    //  k1: N,NE / C,E (frA,fcB)   k3: NW,N / W,C (frA,fcA)
    //  k5: W,C / SW,S (frB,fcA)   k7: C,E / S,SE (frB,fcB)
    const float lut[10] = {
        (float)(0.0 / 255.0), (float)(1.0 / 255.0), (float)(2.0 / 255.0),
        (float)(3.0 / 255.0), (float)(4.0 / 255.0), (float)(5.0 / 255.0),
        (float)(6.0 / 255.0), (float)(7.0 / 255.0), (float)(8.0 / 255.0),
        (float)(9.0 / 255.0)
    };

    float res[4];
#pragma unroll
    for (int i = 0; i < 4; ++i) {
        float colf = (float)(col0 + i);
        float cA_ = colf + OFF_A; float fcA = cA_ - floorf(cA_);
        float cB_ = colf + OFF_B; float fcB = cB_ - floorf(cB_);
        float omcA = 1.0f - fcA;
        float omcB = 1.0f - fcB;

        float vNW = T[i], vN = T[i + 1], vNE = T[i + 2];
        float vW  = M[i], vC = M[i + 1], vE  = M[i + 2];
        float vSW = B[i], vS = B[i + 1], vSE = B[i + 2];

        int b0 = (vE >= vC);
        int b1 = bilin_ge(frA, fcB, omrA, omcB, vN,  vNE, vC,  vE,  vC);
        int b2 = (vN >= vC);
        int b3 = bilin_ge(frA, fcA, omrA, omcA, vNW, vN,  vW,  vC,  vC);
        int b4 = (vW >= vC);
        int b5 = bilin_ge(frB, fcA, omrB, omcA, vW,  vC,  vSW, vS,  vC);
        int b6 = (vS >= vC);
        int b7 = bilin_ge(frB, fcB, omrB, omcB, vC,  vE,  vS,  vSE, vC);

        int ones    = b0 + b1 + b2 + b3 + b4 + b5 + b6 + b7;
        int changes = (b0 ^ b1) + (b1 ^ b2) + (b2 ^ b3) + (b3 ^ b4)
                    + (b4 ^ b5) + (b5 ^ b6) + (b6 ^ b7) + (b7 ^ b0);
        int lbp = (changes <= 2) ? ones : 9;
        res[i] = lut[lbp];
    }

    float4 o;
    o.x = res[0]; o.y = res[1]; o.z = res[2]; o.w = res[3];
    *reinterpret_cast<float4*>(out + ((size_t)q << 2)) = o;
}

extern "C" void kernel_launch(void* const* d_in, const int* in_sizes, int n_in,
                              void* d_out, int out_size, void* d_ws, size_t ws_size,
                              hipStream_t stream) {
    const float* x = (const float*)d_in[0];
    float* out = (float*)d_out;
    int nquads = out_size >> 2;               // 8,388,608
    int blocks = (nquads + 255) / 256;        // 32,768
    lbp_uniform_kernel4<<<blocks, 256, 0, stream>>>(x, out, nquads);
}

// Round 12
// 235.653 us; speedup vs baseline: 1.8343x; 1.1139x over previous
//
#include <hip/hip_runtime.h>
#include <math.h>

// ALL floating-point here must be strict IEEE f32, no FMA contraction.
// (Round-10 lesson: __fadd_rn/__fmul_rn header wrappers pick up contract
// flags from the header's pragma context — use plain ops in THIS file only.)
#pragma clang fp contract(off)

// Exact f32 of the reference's (dr + pad): pad=2, off=np.round(sin(pi/4),5)
#define OFF_A ((float)(2.0 - 0.70711))   // 1.29289 -> f32
#define OFF_B ((float)(2.0 + 0.70711))   // 2.70711 -> f32

static __device__ __forceinline__ float cvt_u8(float v) {
#pragma clang fp contract(off)
    // Reference: clip(floor(x*255), 0, 255); input uniform [0,1) -> clamps
    // are provably no-ops. Strict f32 mul.
    return floorf(v * 255.0f);
}

// Reference bilinear, STRICT f32, token-identical op sequence to the
// round-10/11 passing kernels. Zero fusion.
static __device__ __forceinline__ int bilin_ge(float fr, float fc,
                                               float omr, float omc,
                                               float v00, float v01,
                                               float v10, float v11,
                                               float c) {
#pragma clang fp contract(off)
    float w00 = omr * omc;
    float w01 = omr * fc;
    float w10 = fr * omc;
    float w11 = fr * fc;
    float t0 = w00 * v00;
    float t1 = w01 * v01;
    float t2 = w10 * v10;
    float t3 = w11 * v11;
    float s1 = t0 + t1;
    float s2 = s1 + t2;
    float val = s2 + t3;
    float d = val - c;
    return d >= 0.0f;
}

// One thread = 2 rows x 4 cols of output. 256-entry LDS table maps the packed
// neighbor-bit pattern directly to the final f32 output (uniform test + /255
// folded in): replaces ~33 VALU ops/px with 7 pack ops + 1 ds_read (DS pipe).
__global__ __launch_bounds__(256)
void lbp_kernel8(const float* __restrict__ x, float* __restrict__ out,
                 int nthreads) {
#pragma clang fp contract(off)
    __shared__ float tbl[256];
    {
        // Pattern p, bit k = b_k (ring order). ones = popcount(p);
        // changes = popcount(p XOR rotr8(p)) == sum |b_k - b_{k+1 mod 8}|.
        int p = threadIdx.x;
        int ones = __popc(p);
        int rot = ((p >> 1) | (p << 7)) & 255;
        int changes = __popc(p ^ rot);
        int code = (changes <= 2) ? ones : 9;
        // IEEE correctly-rounded f32 divide == RN(code/255), the exact
        // reference constant. Executed once per block.
        tbl[p] = (float)code / 255.0f;
    }
    __syncthreads();

    int idx = blockIdx.x * 256 + threadIdx.x;
    if (idx >= nthreads) return;

    int quad = idx & 255;              // 256 col-quads per row
    int rpair = (idx >> 8) & 511;      // 512 row-pairs per image
    int ch = idx >> 17;                // channel
    int col0 = quad << 2;
    int row0 = rpair << 1;             // rows row0, row0+1

    const float* img = x + ((size_t)ch << 20);
    const float* p0 = img + ((size_t)row0 << 10);
    const float* p1 = p0 + 1024;
    bool gT = (row0 > 0), gB = (row0 < 1022);
    const float* pT = gT ? p0 - 1024 : p0;   // clamped (values zeroed below)
    const float* pB = gB ? p1 + 1024 : p1;

    bool lv = (col0 > 0), rv = (col0 < 1020);
    int cl = lv ? col0 - 1 : col0;
    int cr = rv ? col0 + 4 : col0 + 3;

    // 4 image rows x 6 columns: [L][x][y][z][w][R]
    float4 t4 = *reinterpret_cast<const float4*>(pT + col0);
    float4 a4 = *reinterpret_cast<const float4*>(p0 + col0);
    float4 b4 = *reinterpret_cast<const float4*>(p1 + col0);
    float4 s4 = *reinterpret_cast<const float4*>(pB + col0);
    float tL = pT[cl], tR = pT[cr];
    float aL = p0[cl], aR = p0[cr];
    float bL = p1[cl], bR = p1[cr];
    float sL = pB[cl], sR = pB[cr];

    float RT[6], R0[6], R1[6], RB[6];
    RT[0] = (gT && lv) ? cvt_u8(tL)   : 0.0f;
    RT[1] = gT         ? cvt_u8(t4.x) : 0.0f;
    RT[2] = gT         ? cvt_u8(t4.y) : 0.0f;
    RT[3] = gT         ? cvt_u8(t4.z) : 0.0f;
    RT[4] = gT         ? cvt_u8(t4.w) : 0.0f;
    RT[5] = (gT && rv) ? cvt_u8(tR)   : 0.0f;
    R0[0] = lv ? cvt_u8(aL) : 0.0f;
    R0[1] = cvt_u8(a4.x);
    R0[2] = cvt_u8(a4.y);
    R0[3] = cvt_u8(a4.z);
    R0[4] = cvt_u8(a4.w);
    R0[5] = rv ? cvt_u8(aR) : 0.0f;
    R1[0] = lv ? cvt_u8(bL) : 0.0f;
    R1[1] = cvt_u8(b4.x);
    R1[2] = cvt_u8(b4.y);
    R1[3] = cvt_u8(b4.z);
    R1[4] = cvt_u8(b4.w);
    R1[5] = rv ? cvt_u8(bR) : 0.0f;
    RB[0] = (gB && lv) ? cvt_u8(sL)   : 0.0f;
    RB[1] = gB         ? cvt_u8(s4.x) : 0.0f;
    RB[2] = gB         ? cvt_u8(s4.y) : 0.0f;
    RB[3] = gB         ? cvt_u8(s4.z) : 0.0f;
    RB[4] = gB         ? cvt_u8(s4.w) : 0.0f;
    RB[5] = (gB && rv) ? cvt_u8(sR)   : 0.0f;

    // Column fractional parts: computed once, shared by both pixel rows.
    // fc = c - floor(c), c = f32(col) + f32(off) — exact reference chain.
    float fcA[4], fcB[4], omcA[4], omcB[4];
#pragma unroll
    for (int i = 0; i < 4; ++i) {
        float colf = (float)(col0 + i);
        float cA_ = colf + OFF_A; fcA[i] = cA_ - floorf(cA_);
        float cB_ = colf + OFF_B; fcB[i] = cB_ - floorf(cB_);
        omcA[i] = 1.0f - fcA[i];
        omcB[i] = 1.0f - fcB[i];
    }

    // k -> (dr,dc): 0:(0,+1) 1:(-.7,+.7) 2:(-1,0) 3:(-.7,-.7)
    //               4:(0,-1) 5:(+.7,-.7) 6:(+1,0) 7:(+.7,+.7)
    // Diagonal corners (v00,v01 / v10,v11):
    //  k1: N,NE / C,E (fr?,fcB)   k3: NW,N / W,C (fr?,fcA)
    //  k5: W,C / SW,S (frB?,fcA)  k7: C,E / S,SE (frB?,fcB)
    float* rows[4] = { RT, R0, R1, RB };
    size_t obase = ((size_t)ch << 20) + ((size_t)row0 << 10) + col0;

#pragma unroll
    for (int j = 0; j < 2; ++j) {
        float rowf = (float)(row0 + j);
        float rA = rowf + OFF_A; float frA = rA - floorf(rA);
        float rB_ = rowf + OFF_B; float frB = rB_ - floorf(rB_);
        float omrA = 1.0f - frA;
        float omrB = 1.0f - frB;
        const float* N = rows[j];
        const float* C = rows[j + 1];
        const float* S = rows[j + 2];

        float res[4];
#pragma unroll
        for (int i = 0; i < 4; ++i) {
            float vNW = N[i], vN = N[i + 1], vNE = N[i + 2];
            float vW  = C[i], vC = C[i + 1], vE  = C[i + 2];
            float vSW = S[i], vS = S[i + 1], vSE = S[i + 2];

            int b0 = (vE >= vC);
            int b1 = bilin_ge(frA, fcB[i], omrA, omcB[i], vN,  vNE, vC,  vE,  vC);
            int b2 = (vN >= vC);
            int b3 = bilin_ge(frA, fcA[i], omrA, omcA[i], vNW, vN,  vW,  vC,  vC);
            int b4 = (vW >= vC);
            int b5 = bilin_ge(frB, fcA[i], omrB, omcA[i], vW,  vC,  vSW, vS,  vC);
            int b6 = (vS >= vC);
            int b7 = bilin_ge(frB, fcB[i], omrB, omcB[i], vC,  vE,  vS,  vSE, vC);

            int pat = b0 | (b1 << 1) | (b2 << 2) | (b3 << 3)
                    | (b4 << 4) | (b5 << 5) | (b6 << 6) | (b7 << 7);
            res[i] = tbl[pat];
        }
        float4 o;
        o.x = res[0]; o.y = res[1]; o.z = res[2]; o.w = res[3];
        *reinterpret_cast<float4*>(out + obase + ((size_t)j << 10)) = o;
    }
}

extern "C" void kernel_launch(void* const* d_in, const int* in_sizes, int n_in,
                              void* d_out, int out_size, void* d_ws, size_t ws_size,
                              hipStream_t stream) {
    const float* x = (const float*)d_in[0];
    float* out = (float*)d_out;
    int nthreads = out_size >> 3;             // 4,194,304 (8 px/thread)
    int blocks = (nthreads + 255) / 256;      // 16,384
    lbp_kernel8<<<blocks, 256, 0, stream>>>(x, out, nthreads);
}